// Round 8
// baseline (553.896 us; speedup 1.0000x reference)
//
#include <hip/hip_runtime.h>

#define TT 20
#define HH 20

typedef float f32x4 __attribute__((ext_vector_type(4)));
typedef short bf16x8 __attribute__((ext_vector_type(8)));
typedef unsigned uint4v __attribute__((ext_vector_type(4)));

__device__ __forceinline__ short f2bf(float f) {
    unsigned u = __float_as_uint(f);
    unsigned r = (u + 0x7fffu + ((u >> 16) & 1u)) >> 16;
    return (short)r;
}
__device__ __forceinline__ float bf2f(short s) {
    return __uint_as_float(((unsigned)(unsigned short)s) << 16);
}

// packed f32x2 -> bf16x2 (RTNE), a -> low half, b -> high half
__device__ __forceinline__ unsigned pk_bf16(float a, float b) {
    unsigned r;
    asm("v_cvt_pk_bf16_f32 %0, %1, %2" : "=v"(r) : "v"(a), "v"(b));
    return r;
}
__device__ __forceinline__ float lo_half(unsigned u) { return __uint_as_float(u << 16); }
__device__ __forceinline__ float hi_half(unsigned u) { return __uint_as_float(u & 0xffff0000u); }

// Build B fragments (hi + residual-lo) from lane-local state.
// Lane (g = lane>>4, n = lane&15): B[k = 8g+e][col]; e<5 -> h[unit 4e+g],
// e=7 -> x (g==0) / 1.0 (g==1) / 0; e=5,6 pad.
__device__ __forceinline__ void build_B(const float (&hn)[5][4], const float (&xv)[4],
                                        float xm, float om,
                                        bf16x8 (&Bhi)[4], bf16x8 (&Blo)[4])
{
    #pragma unroll
    for (int b = 0; b < 4; ++b) {
        const float h0 = hn[0][b], h1 = hn[1][b], h2 = hn[2][b],
                    h3 = hn[3][b], h4 = hn[4][b];
        const float s7 = fmaf(xm, xv[b], om);
        const unsigned u0 = pk_bf16(h0, h1);
        const unsigned u1 = pk_bf16(h2, h3);
        const unsigned u2 = pk_bf16(h4, 0.0f);
        const unsigned u3 = pk_bf16(0.0f, s7);
        const float l0 = h0 - lo_half(u0);
        const float l1 = h1 - hi_half(u0);
        const float l2 = h2 - lo_half(u1);
        const float l3 = h3 - hi_half(u1);
        const float l4 = h4 - lo_half(u2);
        const float l7 = xm * (xv[b] - hi_half(u3));
        const unsigned v0 = pk_bf16(l0, l1);
        const unsigned v1 = pk_bf16(l2, l3);
        const unsigned v2 = pk_bf16(l4, 0.0f);
        const unsigned v3 = pk_bf16(0.0f, l7);
        uint4v uh; uh[0] = u0; uh[1] = u1; uh[2] = u2; uh[3] = u3;
        uint4v ul; ul[0] = v0; ul[1] = v1; ul[2] = v2; ul[3] = v3;
        Bhi[b] = __builtin_bit_cast(bf16x8, uh);
        Blo[b] = __builtin_bit_cast(bf16x8, ul);
    }
}

// Per-unit nonlinearity on one MFMA accumulator (i,f,g,o in regs 0..3).
// i/f/o pre-scaled by -log2e, g by +2log2e at A-build time, so acc feeds
// v_exp_f32 directly. Merged-rcp forms: 5 exp + 2 rcp per unit.
__device__ __forceinline__ void nonlin(const f32x4 a, float& cst, float& hout,
                                       const float TLOG2E)
{
    const float ei = __builtin_amdgcn_exp2f(a[0]);
    const float ef = __builtin_amdgcn_exp2f(a[1]);
    const float eg = __builtin_amdgcn_exp2f(a[2]);
    const float eo = __builtin_amdgcn_exp2f(a[3]);
    const float pi = 1.0f + ei, pf = 1.0f + ef;
    const float pg = 1.0f + eg, po = 1.0f + eo;
    const float pig = pi * pg;
    const float r3  = __builtin_amdgcn_rcpf(pig * pf);
    const float cn  = fmaf(cst, pig, (eg - 1.0f) * pf) * r3;
    cst = cn;
    const float ec = __builtin_amdgcn_exp2f(TLOG2E * cn);
    const float pc = 1.0f + ec;
    hout = (ec - 1.0f) * __builtin_amdgcn_rcpf(po * pc);
}

// 256 threads = 4 independent waves (no barriers). One wave = 64 coords.
// Weights permanently in VGPRs as MFMA A-fragments (hi+lo bf16 split).
// Tile-PAIR processing: 24 MFMAs for tiles {t,t+1}, then 8 independent
// nonlinearity chains — doubles the ILP available to hide ~16-cyc trans
// latency (R6's per-tile structure had only 4 chains; 24% stall).
__global__ __launch_bounds__(256)
void coord_lstm_mfma(const float* __restrict__ grads,
                     const float* __restrict__ w_ih,
                     const float* __restrict__ w_hh,
                     const float* __restrict__ b_ih,
                     const float* __restrict__ b_hh,
                     const float* __restrict__ w_fc,
                     const float* __restrict__ b_fc,
                     float* __restrict__ out,
                     int N)
{
    const int lane = threadIdx.x & 63;
    const int g = lane >> 4;
    const int n = lane & 15;
    const long long base = ((long long)blockIdx.x * 4 + (threadIdx.x >> 6)) * 64;
    if (base >= N) return;

    const float LOG2E  = 1.4426950408889634f;
    const float TLOG2E = 2.8853900817779268f;
    const float xm = (g == 0) ? 1.0f : 0.0f;
    const float om = (g == 1) ? 1.0f : 0.0f;

    // ---- A fragments, built once. Tiles 0..4: row r=16*tA+n -> unit r>>2,
    // gate r&3 (0=i 1=f 2=g 3=o), source row gate*HH+unit, pre-scaled.
    // Tile 5: output projection (w_fc row 0, b_fc in the 1-column), unscaled.
    bf16x8 Ahi[6], Alo[6];
    #pragma unroll
    for (int tA = 0; tA < 6; ++tA) {
        bf16x8 ah, al;
        #pragma unroll
        for (int e = 0; e < 8; ++e) {
            float v = 0.0f;
            if (tA < 5) {
                const int r = 16 * tA + n;
                const int u_r = r >> 2;
                const int gate = r & 3;
                const float scale = (gate == 2) ? TLOG2E : -LOG2E;
                const int row_w = gate * HH + u_r;
                if (e < 5)       v = scale * w_hh[row_w * HH + (4 * e + g)];
                else if (e == 7) v = (g == 0) ? scale * w_ih[row_w]
                                   : (g == 1) ? scale * (b_ih[row_w] + b_hh[row_w]) : 0.0f;
            } else {
                if (e < 5)       v = (n == 0) ? w_fc[4 * e + g] : 0.0f;
                else if (e == 7) v = (g == 1 && n == 0) ? b_fc[0] : 0.0f;
            }
            const short hi = f2bf(v);
            ah[e] = hi;
            al[e] = f2bf(v - bf2f(hi));
        }
        Ahi[tA] = ah; Alo[tA] = al;
    }

    const f32x4 zero4 = {0.0f, 0.0f, 0.0f, 0.0f};

    // clamped coordinates + store guards, then everything incremental
    long long cc[4]; bool wr[4];
    #pragma unroll
    for (int b = 0; b < 4; ++b) {
        long long c0 = base + 16 * b + n;
        wr[b] = (c0 < N);
        cc[b] = wr[b] ? c0 : (long long)(N - 1);
    }
    const float* gp0 = grads + cc[0];
    const float* gp1 = grads + cc[1];
    const float* gp2 = grads + cc[2];
    const float* gp3 = grads + cc[3];
    float* op0 = out + cc[0];
    float* op1 = out + cc[1];
    float* op2 = out + cc[2];
    float* op3 = out + cc[3];

    float c[5][4], hn[5][4];
    #pragma unroll
    for (int t5 = 0; t5 < 5; ++t5)
        #pragma unroll
        for (int b = 0; b < 4; ++b) { c[t5][b] = 0.0f; hn[t5][b] = 0.0f; }

    float xv[4];
    xv[0] = *gp0; gp0 += N;
    xv[1] = *gp1; gp1 += N;
    xv[2] = *gp2; gp2 += N;
    xv[3] = *gp3; gp3 += N;        // now point at t=1

    bf16x8 Bhi[4], Blo[4];
    build_B(hn, xv, xm, om, Bhi, Blo);   // [h(-1)=0 ; x(0); 1]

    #pragma unroll 1
    for (int t = 0; t < TT; ++t) {
        // prefetch x(t+1); last iter feeds 0 (pad slot, multiplied by 0 in A)
        float xn[4];
        if (t < TT - 1) {
            xn[0] = *gp0; gp0 += N;
            xn[1] = *gp1; gp1 += N;
            xn[2] = *gp2; gp2 += N;
            xn[3] = *gp3; gp3 += N;
        } else {
            xn[0] = 0.0f; xn[1] = 0.0f; xn[2] = 0.0f; xn[3] = 0.0f;
        }

        // ---- tile pair {0,1}: 24 MFMAs, then 8 independent nonlin chains
        #pragma unroll
        for (int tp = 0; tp < 2; ++tp) {
            const int tile0 = 2 * tp;
            const int tile1 = 2 * tp + 1;
            f32x4 accA[4], accB[4];
            #pragma unroll
            for (int b = 0; b < 4; ++b) {
                f32x4 a = __builtin_amdgcn_mfma_f32_16x16x32_bf16(Ahi[tile0], Bhi[b], zero4, 0, 0, 0);
                a = __builtin_amdgcn_mfma_f32_16x16x32_bf16(Ahi[tile0], Blo[b], a, 0, 0, 0);
                a = __builtin_amdgcn_mfma_f32_16x16x32_bf16(Alo[tile0], Bhi[b], a, 0, 0, 0);
                accA[b] = a;
                f32x4 d = __builtin_amdgcn_mfma_f32_16x16x32_bf16(Ahi[tile1], Bhi[b], zero4, 0, 0, 0);
                d = __builtin_amdgcn_mfma_f32_16x16x32_bf16(Ahi[tile1], Blo[b], d, 0, 0, 0);
                d = __builtin_amdgcn_mfma_f32_16x16x32_bf16(Alo[tile1], Bhi[b], d, 0, 0, 0);
                accB[b] = d;
            }
            #pragma unroll
            for (int b = 0; b < 4; ++b) {
                nonlin(accA[b], c[tile0][b], hn[tile0][b], TLOG2E);
                nonlin(accB[b], c[tile1][b], hn[tile1][b], TLOG2E);
            }
        }
        // ---- tile 4 alone
        {
            f32x4 acc4[4];
            #pragma unroll
            for (int b = 0; b < 4; ++b) {
                f32x4 a = __builtin_amdgcn_mfma_f32_16x16x32_bf16(Ahi[4], Bhi[b], zero4, 0, 0, 0);
                a = __builtin_amdgcn_mfma_f32_16x16x32_bf16(Ahi[4], Blo[b], a, 0, 0, 0);
                a = __builtin_amdgcn_mfma_f32_16x16x32_bf16(Alo[4], Bhi[b], a, 0, 0, 0);
                acc4[b] = a;
            }
            #pragma unroll
            for (int b = 0; b < 4; ++b)
                nonlin(acc4[b], c[4][b], hn[4][b], TLOG2E);
        }

        // B_new = [h(t); x(t+1); 1]
        build_B(hn, xn, xm, om, Bhi, Blo);

        // out(t) = w_fc . h(t) + b_fc   (tile 5 -> lanes g==0, reg 0)
        f32x4 ov[4];
        #pragma unroll
        for (int b = 0; b < 4; ++b) {
            f32x4 o = __builtin_amdgcn_mfma_f32_16x16x32_bf16(Ahi[5], Bhi[b], zero4, 0, 0, 0);
            o = __builtin_amdgcn_mfma_f32_16x16x32_bf16(Ahi[5], Blo[b], o, 0, 0, 0);
            o = __builtin_amdgcn_mfma_f32_16x16x32_bf16(Alo[5], Bhi[b], o, 0, 0, 0);
            ov[b] = o;
        }
        if (g == 0) {
            if (wr[0]) *op0 = ov[0][0];
            if (wr[1]) *op1 = ov[1][0];
            if (wr[2]) *op2 = ov[2][0];
            if (wr[3]) *op3 = ov[3][0];
        }
        op0 += N; op1 += N; op2 += N; op3 += N;
    }
}

extern "C" void kernel_launch(void* const* d_in, const int* in_sizes, int n_in,
                              void* d_out, int out_size, void* d_ws, size_t ws_size,
                              hipStream_t stream) {
    const float* grads = (const float*)d_in[0];
    const float* w_ih  = (const float*)d_in[1];
    const float* w_hh  = (const float*)d_in[2];
    const float* b_ih  = (const float*)d_in[3];
    const float* b_hh  = (const float*)d_in[4];
    const float* w_fc  = (const float*)d_in[5];
    const float* b_fc  = (const float*)d_in[6];
    float* out = (float*)d_out;

    const int N = in_sizes[0] / TT;            // grads is (T, N)
    const long long waves = ((long long)N + 63) / 64;
    const int blocks = (int)((waves + 3) / 4); // 4 waves per 256-thread block
    coord_lstm_mfma<<<blocks, 256, 0, stream>>>(grads, w_ih, w_hh, b_ih, b_hh,
                                                w_fc, b_fc, out, N);
}

// Round 9
// 430.926 us; speedup vs baseline: 1.2854x; 1.2854x over previous
//
#include <hip/hip_runtime.h>

#define TT 20
#define HH 20

typedef float f32x4 __attribute__((ext_vector_type(4)));
typedef short bf16x8 __attribute__((ext_vector_type(8)));
typedef unsigned uint4v __attribute__((ext_vector_type(4)));

__device__ __forceinline__ short f2bf(float f) {
    unsigned u = __float_as_uint(f);
    unsigned r = (u + 0x7fffu + ((u >> 16) & 1u)) >> 16;
    return (short)r;
}

// packed f32x2 -> bf16x2 (RTNE), a -> low half, b -> high half
__device__ __forceinline__ unsigned pk_bf16(float a, float b) {
    unsigned r;
    asm("v_cvt_pk_bf16_f32 %0, %1, %2" : "=v"(r) : "v"(a), "v"(b));
    return r;
}

// Build B fragment (pure bf16, no residual split) from lane-local state.
// Lane (g = lane>>4, n = lane&15): B[k = 8g+e][col]; e<5 -> h[unit 4e+g],
// e=7 -> x (g==0) / 1.0 (g==1) / 0; e=5,6 pad. 4 cvt_pk + 1 fma per frag.
__device__ __forceinline__ void build_B(const float (&hn)[5][4], const float (&xv)[4],
                                        float xm, float om, bf16x8 (&Bhi)[4])
{
    #pragma unroll
    for (int b = 0; b < 4; ++b) {
        const float s7 = fmaf(xm, xv[b], om);
        uint4v uh;
        uh[0] = pk_bf16(hn[0][b], hn[1][b]);
        uh[1] = pk_bf16(hn[2][b], hn[3][b]);
        uh[2] = pk_bf16(hn[4][b], 0.0f);
        uh[3] = pk_bf16(0.0f, s7);
        Bhi[b] = __builtin_bit_cast(bf16x8, uh);
    }
}

// Per-unit nonlinearity on one MFMA accumulator (i,f,g,o in regs 0..3).
// i/f/o pre-scaled by -log2e, g by +2log2e at A-build time, so acc feeds
// v_exp_f32 directly. Merged-rcp forms: 5 exp + 2 rcp per unit.
__device__ __forceinline__ void nonlin(const f32x4 a, float& cst, float& hout,
                                       const float TLOG2E)
{
    const float ei = __builtin_amdgcn_exp2f(a[0]);
    const float ef = __builtin_amdgcn_exp2f(a[1]);
    const float eg = __builtin_amdgcn_exp2f(a[2]);
    const float eo = __builtin_amdgcn_exp2f(a[3]);
    const float pi = 1.0f + ei, pf = 1.0f + ef;
    const float pg = 1.0f + eg, po = 1.0f + eo;
    const float pig = pi * pg;
    const float r3  = __builtin_amdgcn_rcpf(pig * pf);
    const float cn  = fmaf(cst, pig, (eg - 1.0f) * pf) * r3;
    cst = cn;
    const float ec = __builtin_amdgcn_exp2f(TLOG2E * cn);
    const float pc = 1.0f + ec;
    hout = (ec - 1.0f) * __builtin_amdgcn_rcpf(po * pc);
}

// 256 threads = 4 independent waves. One wave = 64 coords, all 20 steps.
// Pure-bf16 MFMA path (no hi/lo residual split): weights ONCE in 24 VGPRs
// (Ahi[6]), 24 MFMAs/step, minimal build_B. Total (V+A)GPR target ~110 so
// 4 waves/SIMD fit the 512-reg unified pool (R6-R8 sat at ~256 regs -> 2
// waves/SIMD -> 75% latency stall; residency is the lever, not ILP).
__global__ __launch_bounds__(256)
void coord_lstm_mfma(const float* __restrict__ grads,
                     const float* __restrict__ w_ih,
                     const float* __restrict__ w_hh,
                     const float* __restrict__ b_ih,
                     const float* __restrict__ b_hh,
                     const float* __restrict__ w_fc,
                     const float* __restrict__ b_fc,
                     float* __restrict__ out,
                     int N)
{
    const int lane = threadIdx.x & 63;
    const int g = lane >> 4;
    const int n = lane & 15;
    const long long base = ((long long)blockIdx.x * 4 + (threadIdx.x >> 6)) * 64;
    if (base >= N) return;

    const float LOG2E  = 1.4426950408889634f;
    const float TLOG2E = 2.8853900817779268f;
    const float xm = (g == 0) ? 1.0f : 0.0f;
    const float om = (g == 1) ? 1.0f : 0.0f;

    // ---- A fragments (bf16, RTNE-rounded), built once. Tiles 0..4: row
    // r=16*tA+n -> unit r>>2, gate r&3 (0=i 1=f 2=g 3=o), source row
    // gate*HH+unit, pre-scaled. Tile 5: w_fc / b_fc, unscaled.
    bf16x8 Ahi[6];
    #pragma unroll
    for (int tA = 0; tA < 6; ++tA) {
        bf16x8 ah;
        #pragma unroll
        for (int e = 0; e < 8; ++e) {
            float v = 0.0f;
            if (tA < 5) {
                const int r = 16 * tA + n;
                const int u_r = r >> 2;
                const int gate = r & 3;
                const float scale = (gate == 2) ? TLOG2E : -LOG2E;
                const int row_w = gate * HH + u_r;
                if (e < 5)       v = scale * w_hh[row_w * HH + (4 * e + g)];
                else if (e == 7) v = (g == 0) ? scale * w_ih[row_w]
                                   : (g == 1) ? scale * (b_ih[row_w] + b_hh[row_w]) : 0.0f;
            } else {
                if (e < 5)       v = (n == 0) ? w_fc[4 * e + g] : 0.0f;
                else if (e == 7) v = (g == 1 && n == 0) ? b_fc[0] : 0.0f;
            }
            ah[e] = f2bf(v);
        }
        Ahi[tA] = ah;
    }

    const f32x4 zero4 = {0.0f, 0.0f, 0.0f, 0.0f};

    // clamped coordinates + store guards, then everything incremental
    long long cc[4]; bool wr[4];
    #pragma unroll
    for (int b = 0; b < 4; ++b) {
        long long c0 = base + 16 * b + n;
        wr[b] = (c0 < N);
        cc[b] = wr[b] ? c0 : (long long)(N - 1);
    }
    const float* gp0 = grads + cc[0];
    const float* gp1 = grads + cc[1];
    const float* gp2 = grads + cc[2];
    const float* gp3 = grads + cc[3];
    float* op0 = out + cc[0];
    float* op1 = out + cc[1];
    float* op2 = out + cc[2];
    float* op3 = out + cc[3];

    float c[5][4], hn[5][4];
    #pragma unroll
    for (int t5 = 0; t5 < 5; ++t5)
        #pragma unroll
        for (int b = 0; b < 4; ++b) { c[t5][b] = 0.0f; hn[t5][b] = 0.0f; }

    float xv[4];
    xv[0] = *gp0; gp0 += N;
    xv[1] = *gp1; gp1 += N;
    xv[2] = *gp2; gp2 += N;
    xv[3] = *gp3; gp3 += N;        // now point at t=1

    bf16x8 Bhi[4];
    build_B(hn, xv, xm, om, Bhi);  // [h(-1)=0 ; x(0); 1]

    #pragma unroll 1
    for (int t = 0; t < TT; ++t) {
        // prefetch x(t+1); last iter feeds 0 (pad slot, A column is zero)
        float xn[4];
        if (t < TT - 1) {
            xn[0] = *gp0; gp0 += N;
            xn[1] = *gp1; gp1 += N;
            xn[2] = *gp2; gp2 += N;
            xn[3] = *gp3; gp3 += N;
        } else {
            xn[0] = 0.0f; xn[1] = 0.0f; xn[2] = 0.0f; xn[3] = 0.0f;
        }

        // per tile: 4 MFMAs then lane-local nonlinearity (i,f,g,o in regs 0..3)
        #pragma unroll
        for (int tile = 0; tile < 5; ++tile) {
            f32x4 acc[4];
            #pragma unroll
            for (int b = 0; b < 4; ++b)
                acc[b] = __builtin_amdgcn_mfma_f32_16x16x32_bf16(Ahi[tile], Bhi[b], zero4, 0, 0, 0);
            #pragma unroll
            for (int b = 0; b < 4; ++b)
                nonlin(acc[b], c[tile][b], hn[tile][b], TLOG2E);
        }

        // B_new = [h(t); x(t+1); 1]
        build_B(hn, xn, xm, om, Bhi);

        // out(t) = w_fc . h(t) + b_fc   (tile 5 -> lanes g==0, reg 0)
        f32x4 ov[4];
        #pragma unroll
        for (int b = 0; b < 4; ++b)
            ov[b] = __builtin_amdgcn_mfma_f32_16x16x32_bf16(Ahi[5], Bhi[b], zero4, 0, 0, 0);

        if (g == 0) {
            if (wr[0]) *op0 = ov[0][0];
            if (wr[1]) *op1 = ov[1][0];
            if (wr[2]) *op2 = ov[2][0];
            if (wr[3]) *op3 = ov[3][0];
        }
        op0 += N; op1 += N; op2 += N; op3 += N;
    }
}

extern "C" void kernel_launch(void* const* d_in, const int* in_sizes, int n_in,
                              void* d_out, int out_size, void* d_ws, size_t ws_size,
                              hipStream_t stream) {
    const float* grads = (const float*)d_in[0];
    const float* w_ih  = (const float*)d_in[1];
    const float* w_hh  = (const float*)d_in[2];
    const float* b_ih  = (const float*)d_in[3];
    const float* b_hh  = (const float*)d_in[4];
    const float* w_fc  = (const float*)d_in[5];
    const float* b_fc  = (const float*)d_in[6];
    float* out = (float*)d_out;

    const int N = in_sizes[0] / TT;            // grads is (T, N)
    const long long waves = ((long long)N + 63) / 64;
    const int blocks = (int)((waves + 3) / 4); // 4 waves per 256-thread block
    coord_lstm_mfma<<<blocks, 256, 0, stream>>>(grads, w_ih, w_hh, b_ih, b_hh,
                                                w_fc, b_fc, out, N);
}